// Round 4
// baseline (361.694 us; speedup 1.0000x reference)
//
#include <hip/hip_runtime.h>
#include <hip/hip_bf16.h>

typedef unsigned short u16;
typedef unsigned int u32;
typedef __attribute__((ext_vector_type(8))) short short8;
typedef __attribute__((ext_vector_type(4))) float float4v;

#define T_DIM 2048
#define D_DIM 2048
#define N_DIM 11264
#define BD    5632
#define KE    256   // extra K from LoRA fold-in (L*R = 16*16)

__device__ __forceinline__ u16 f2bf(float f) {
    union { float f; u32 u; } v; v.f = f;
    u32 u = v.u;
    return (u16)((u + 0x7fffu + ((u >> 16) & 1u)) >> 16);  // RNE, inputs finite
}

__device__ __forceinline__ void gld16(const u16* g, u16* l) {
    // async global->LDS, 16B per lane; LDS dest = wave-uniform base + lane*16
    __builtin_amdgcn_global_load_lds((const __attribute__((address_space(1))) void*)g,
                                     (__attribute__((address_space(3))) void*)l, 16, 0, 0);
}

// ---------------------------------------------------------------------------
// Prep kernel (f32 inputs), block ranges (latency-heavy parts first):
//  bid [0,2048):      xa[t] = x[t,:].A[l_t] (f32, coalesced wave loads),
//                     scatter to dense xahat0/xahat1 (T x 256 bf16)
//  bid [2048,4864):   transpose B (256 x 11264 f32) -> BT (11264 x 256 bf16)
//  bid [4864,5376):   X f32 -> Xb bf16 (32 elems/thread)
//  bid [5376,8192):   W f32 -> Wb bf16 (32 elems/thread)
// ---------------------------------------------------------------------------
__global__ __launch_bounds__(256) void prep_kernel(
    const float* __restrict__ Xf, const float* __restrict__ Wf,
    const float* __restrict__ Af, const float* __restrict__ Bf,
    const int* __restrict__ widx,
    u16* __restrict__ Wb, u16* __restrict__ Xb,
    u16* __restrict__ XH0, u16* __restrict__ XH1, u16* __restrict__ BT)
{
    const int bid = blockIdx.x;
    const int tid = threadIdx.x;

    __shared__ float lx[D_DIM];          // staged x row (8 KB)
    __shared__ float red[4][8][4];
    __shared__ float xa[32];
    __shared__ u16 tile[32][33];

    if (bid < 2048) {
        // ---- xa for token t ----
        const int t = bid;
        const int l = widx[t];
        const float4* xr = (const float4*)(Xf + (size_t)t * D_DIM);
        ((float4*)lx)[tid]       = xr[tid];
        ((float4*)lx)[tid + 256] = xr[tid + 256];
        __syncthreads();

        const int wave = tid >> 6, lane = tid & 63;
        const int rowg = lane >> 3, chunk = lane & 7;
        // wave-load: 8 consecutive rows x 128 B, fully coalesced 1 KB
        const float* abase = Af + (size_t)l * (D_DIM * 32) + chunk * 4;
        float accx = 0.f, accy = 0.f, accz = 0.f, accw = 0.f;
#pragma unroll 4
        for (int i = 0; i < 64; ++i) {
            const int row = wave * 512 + i * 8 + rowg;
            const float4 av = *(const float4*)(abase + (size_t)row * 32);
            const float xf = lx[row];
            accx += xf * av.x; accy += xf * av.y;
            accz += xf * av.z; accw += xf * av.w;
        }
        // reduce across the 8 rowgroups (xor 8/16/32)
#pragma unroll
        for (int off = 8; off <= 32; off <<= 1) {
            accx += __shfl_xor(accx, off);
            accy += __shfl_xor(accy, off);
            accz += __shfl_xor(accz, off);
            accw += __shfl_xor(accw, off);
        }
        if (rowg == 0) {
            red[wave][chunk][0] = accx; red[wave][chunk][1] = accy;
            red[wave][chunk][2] = accz; red[wave][chunk][3] = accw;
        }
        __syncthreads();
        if (tid < 32) {
            const int c = tid >> 2, j = tid & 3;
            xa[c * 4 + j] = red[0][c][j] + red[1][c][j] + red[2][c][j] + red[3][c][j];
        }
        __syncthreads();
        // scatter: k = tid; xahat_h[t, l'*16+r] = (l'==l) ? xa[h*16+r] : 0
        const int k = tid, kl = k >> 4, r = k & 15;
        const bool hit = (kl == l);
        XH0[(size_t)t * KE + k] = hit ? f2bf(xa[r])      : (u16)0;
        XH1[(size_t)t * KE + k] = hit ? f2bf(xa[16 + r]) : (u16)0;
    } else if (bid < 4864) {
        // ---- 32x32 tiled transpose + convert: BT[n,k] = bf16(B[k,n]) ----
        const int b = bid - 2048;
        const int nb = b >> 3;   // 0..351
        const int kb = b & 7;    // 0..7
        const int tx = tid & 31, ty = tid >> 5;
        const int n = nb * 32 + tx;
#pragma unroll
        for (int i = 0; i < 4; ++i) {
            const int kk = kb * 32 + ty + i * 8;
            tile[ty + i * 8][tx] = f2bf(Bf[(size_t)kk * N_DIM + n]);
        }
        __syncthreads();
        const int k2 = kb * 32 + tx;
#pragma unroll
        for (int i = 0; i < 4; ++i) {
            const int n2 = nb * 32 + ty + i * 8;
            BT[(size_t)n2 * KE + k2] = tile[tx][ty + i * 8];
        }
    } else if (bid < 5376) {
        // ---- X convert: 32 f32/thread ----
        const size_t base = ((size_t)(bid - 4864) * 256 + tid) * 32;
        const float4* p = (const float4*)(Xf + base);
        float4 v[8];
#pragma unroll
        for (int i = 0; i < 8; ++i) v[i] = p[i];
#pragma unroll
        for (int i = 0; i < 4; ++i) {
            short8 o;
            o[0] = (short)f2bf(v[2*i].x);   o[1] = (short)f2bf(v[2*i].y);
            o[2] = (short)f2bf(v[2*i].z);   o[3] = (short)f2bf(v[2*i].w);
            o[4] = (short)f2bf(v[2*i+1].x); o[5] = (short)f2bf(v[2*i+1].y);
            o[6] = (short)f2bf(v[2*i+1].z); o[7] = (short)f2bf(v[2*i+1].w);
            *(short8*)(Xb + base + i * 8) = o;
        }
    } else {
        // ---- W convert: 32 f32/thread ----
        const size_t base = ((size_t)(bid - 5376) * 256 + tid) * 32;
        const float4* p = (const float4*)(Wf + base);
        float4 v[8];
#pragma unroll
        for (int i = 0; i < 8; ++i) v[i] = p[i];
#pragma unroll
        for (int i = 0; i < 4; ++i) {
            short8 o;
            o[0] = (short)f2bf(v[2*i].x);   o[1] = (short)f2bf(v[2*i].y);
            o[2] = (short)f2bf(v[2*i].z);   o[3] = (short)f2bf(v[2*i].w);
            o[4] = (short)f2bf(v[2*i+1].x); o[5] = (short)f2bf(v[2*i+1].y);
            o[6] = (short)f2bf(v[2*i+1].z); o[7] = (short)f2bf(v[2*i+1].w);
            *(short8*)(Wb + base + i * 8) = o;
        }
    }
}

// ---------------------------------------------------------------------------
// Main GEMM: out[m,n] = sum_k xb[m,k] wb[n,k]  (K=2048, bf16)
//                     + sum_k xahat_h[m,k] BT[n,k]  (K=256, h by n-half)
//
// 256x256 tile, BK=32, 512 threads = 8 waves (2M x 4N), per-wave 128x64 out.
// 72 K-tiles (64 main + 8 LoRA).
//
// DEEP pipeline, ring of 4 tile-slots per operand (4 x 8KB x 2 = 128 KB):
//   during tile kt, stage tile kt+3 (slot (kt+3)&3 = freed by tile kt-1).
//   Loads get ~2 full tiles (~3400 cyc) of latency cover; the per-tile wait
//   is s_waitcnt vmcnt(8) (tiles kt+2, kt+3 stay in flight) -- NEVER a
//   drain-to-0 in steady state (the m218-measured +38-73% lever).
// Two phases per tile, each {ds_read frags || stage 2 gld16 -> [vmcnt] ->
//   s_barrier -> lgkmcnt(0) -> 16 MFMA (setprio 1) -> s_barrier}:
//   P0: A rows 0-3 (4 rd) + B cols 0-3 (4 rd), stage A(kt+3)
//   P1: A rows 4-7 (4 rd),                   stage B(kt+3), vmcnt(8|4|0)
// LDS layout per slot: [256 rows][32 k] u16, 64B rows. Swizzle: physical
// 16B chunk p of row r holds logical chunk p ^ ((r>>1)&3), staged via
// pre-swizzled global source (LDS dest lane-linear as gld16 requires).
// Fragment ds_read_b128 then lands exactly 2 lanes per 16B bank-granule
// (2-way = free, m136).
// ---------------------------------------------------------------------------
__global__ __launch_bounds__(512, 2) void gemm_kernel(
    const u16* __restrict__ X, const u16* __restrict__ W,
    const u16* __restrict__ XH0, const u16* __restrict__ XH1,
    const u16* __restrict__ BT, float* __restrict__ OUT)
{
    __shared__ __align__(16) u16 lsA[4][256 * 32];  // 64 KB ring (A)
    __shared__ __align__(16) u16 lsB[4][256 * 32];  // 64 KB ring (B)

    const int tid  = threadIdx.x;
    const int lane = tid & 63;
    const int wave = tid >> 6;          // 0..7
    const int wm   = wave >> 2;         // 0..1  (M half)
    const int wn   = wave & 3;          // 0..3  (N quarter)
    const int q    = lane >> 4;         // 0..3
    const int c16  = lane & 15;

    // XCD-chunked mapping: XCD x owns bm=x, sweeps bn -> A panel L2-resident
    const int bid = blockIdx.x;
    const int bm  = bid & 7;
    const int bn  = bid >> 3;           // 0..43
    const int m0  = bm * 256, n0 = bn * 256;

    // ---- staging geometry: per gld16, wave covers 16 rows x 64B ----
    const int prow = lane >> 2;                  // phys row within 16-row span
    const int gch  = (lane & 3) ^ ((lane >> 3) & 3);   // pre-swizzled src chunk
    const u16* XH = (n0 < BD) ? XH0 : XH1;       // tiles never straddle halves

    const size_t rA = (size_t)(m0 + wave * 16 + prow);
    const size_t rB = (size_t)(n0 + wave * 16 + prow);
    const u16* gA = X  + rA * D_DIM + gch * 8;
    const u16* gB = W  + rB * D_DIM + gch * 8;
    const u16* eA = XH + rA * KE    + gch * 8;
    const u16* eB = BT + rB * KE    + gch * 8;
    const int ldsst = (wave * 16) * 32;          // wave's row base (u16 idx)

    float4v acc[8][4] = {};
    short8 af[4], bf[4];

    // fragment read offsets (u16 idx within a slot); p = swizzled chunk
    const int p  = q ^ ((c16 >> 1) & 3);
    const int fa = (wm * 128 + c16) * 32 + p * 8;
    const int fb = (wn * 64  + c16) * 32 + p * 8;

    auto stageA = [&](int t) {
        if (t >= 72) return;
        u16* dst = &lsA[t & 3][0] + ldsst;
        if (t < 64) {
            const u16* s = gA + t * 32;
            gld16(s, dst);
            gld16(s + (size_t)128 * D_DIM, dst + 128 * 32);
        } else {
            const u16* s = eA + (t - 64) * 32;
            gld16(s, dst);
            gld16(s + (size_t)128 * KE, dst + 128 * 32);
        }
    };
    auto stageB = [&](int t) {
        if (t >= 72) return;
        u16* dst = &lsB[t & 3][0] + ldsst;
        if (t < 64) {
            const u16* s = gB + t * 32;
            gld16(s, dst);
            gld16(s + (size_t)128 * D_DIM, dst + 128 * 32);
        } else {
            const u16* s = eB + (t - 64) * 32;
            gld16(s, dst);
            gld16(s + (size_t)128 * KE, dst + 128 * 32);
        }
    };

    auto rdA = [&](const u16* la, int h) {
#pragma unroll
        for (int j = 0; j < 4; ++j)
            af[j] = *(const short8*)(la + fa + (h * 4 + j) * 512);
    };
    auto rdB = [&](const u16* lb) {
#pragma unroll
        for (int f = 0; f < 4; ++f)
            bf[f] = *(const short8*)(lb + fb + f * 512);
    };
    auto mma16 = [&](int h) {
        __builtin_amdgcn_s_setprio(1);
#pragma unroll
        for (int j = 0; j < 4; ++j)
#pragma unroll
            for (int f = 0; f < 4; ++f)
                acc[h * 4 + j][f] = __builtin_amdgcn_mfma_f32_16x16x32_bf16(
                    af[j], bf[f], acc[h * 4 + j][f], 0, 0, 0);
        __builtin_amdgcn_s_setprio(0);
        __builtin_amdgcn_sched_barrier(0);
    };

#define SB0()   __builtin_amdgcn_sched_barrier(0)
#define BAR()   do { SB0(); __builtin_amdgcn_s_barrier(); SB0(); } while (0)
#define LGKM0() do { asm volatile("s_waitcnt lgkmcnt(0)" ::: "memory"); SB0(); } while (0)

    // prologue: stage tiles 0,1,2 (12 gld16); wait oldest 4 (= tile 0)
    stageA(0); stageB(0); stageA(1); stageB(1); stageA(2); stageB(2);
    asm volatile("s_waitcnt vmcnt(8)" ::: "memory");
    BAR();

    for (int kt = 0; kt < 72; ++kt) {
        const u16* la = &lsA[kt & 3][0];
        const u16* lb = &lsB[kt & 3][0];

        // ---- phase 0: A rows 0-3 x B cols 0-3 ----
        rdA(la, 0); rdB(lb);
        SB0();
        stageA(kt + 3);
        SB0();
        BAR();
        LGKM0();
        mma16(0);
        BAR();

        // ---- phase 1: A rows 4-7 x B cols 0-3 ----
        rdA(la, 1);
        SB0();
        stageB(kt + 3);
        SB0();
        if (kt < 69) {
            asm volatile("s_waitcnt vmcnt(8)" ::: "memory");   // tile kt+1 landed
        } else if (kt == 69) {
            asm volatile("s_waitcnt vmcnt(4)" ::: "memory");   // tile 70 landed
        } else if (kt == 70) {
            asm volatile("s_waitcnt vmcnt(0)" ::: "memory");   // tile 71 landed
        }
        SB0();
        BAR();
        LGKM0();
        mma16(1);
        BAR();
    }

#undef SB0
#undef BAR
#undef LGKM0

    // epilogue: C/D layout col = lane&15, row = (lane>>4)*4 + reg
#pragma unroll
    for (int fm = 0; fm < 8; ++fm) {
        const size_t row = (size_t)(m0 + wm * 128 + fm * 16 + q * 4);
#pragma unroll
        for (int fn = 0; fn < 4; ++fn) {
            const int col = n0 + wn * 64 + fn * 16 + c16;
#pragma unroll
            for (int r = 0; r < 4; ++r)
                OUT[(row + r) * N_DIM + col] = acc[fm][fn][r];
        }
    }
}

extern "C" void kernel_launch(void* const* d_in, const int* in_sizes, int n_in,
                              void* d_out, int out_size, void* d_ws, size_t ws_size,
                              hipStream_t stream) {
    const float* Xf  = (const float*)d_in[0];   // (2048, 2048) f32
    const float* Wf  = (const float*)d_in[1];   // (11264, 2048) f32
    const float* Af  = (const float*)d_in[2];   // (16, 2048, 32) f32
    const float* Bf  = (const float*)d_in[3];   // (16, 16, 11264) f32
    const int* widx  = (const int*)d_in[4];     // (2048,) int32 (JAX x64 off)
    float* OUT = (float*)d_out;                 // (2048, 11264) f32

    u16* Wb  = (u16*)d_ws;                            // 11264x2048 bf16 (46.1 MB)
    u16* Xb  = Wb + (size_t)N_DIM * D_DIM;            // 2048x2048 bf16 (8.4 MB)
    u16* XH0 = Xb + (size_t)T_DIM * D_DIM;            // 2048x256 bf16 (1 MB)
    u16* XH1 = XH0 + (size_t)T_DIM * KE;              // 2048x256 bf16 (1 MB)
    u16* BT  = XH1 + (size_t)T_DIM * KE;              // 11264x256 bf16 (5.5 MB)

    prep_kernel<<<dim3(8192), dim3(256), 0, stream>>>(Xf, Wf, Af, Bf, widx,
                                                      Wb, Xb, XH0, XH1, BT);
    gemm_kernel<<<dim3(352), dim3(512), 0, stream>>>(
        Xb, Wb, XH0, XH1, BT, OUT);
}

// Round 5
// 330.750 us; speedup vs baseline: 1.0936x; 1.0936x over previous
//
#include <hip/hip_runtime.h>
#include <hip/hip_bf16.h>

typedef unsigned short u16;
typedef unsigned int u32;
typedef __attribute__((ext_vector_type(8))) short short8;
typedef __attribute__((ext_vector_type(4))) float float4v;

#define T_DIM 2048
#define D_DIM 2048
#define N_DIM 11264
#define BD    5632
#define KE    256   // extra K from LoRA fold-in (L*R = 16*16)

__device__ __forceinline__ u16 f2bf(float f) {
    union { float f; u32 u; } v; v.f = f;
    u32 u = v.u;
    return (u16)((u + 0x7fffu + ((u >> 16) & 1u)) >> 16);  // RNE, inputs finite
}

__device__ __forceinline__ void gld16(const u16* g, u16* l) {
    // async global->LDS, 16B per lane; LDS dest = wave-uniform base + lane*16
    __builtin_amdgcn_global_load_lds((const __attribute__((address_space(1))) void*)g,
                                     (__attribute__((address_space(3))) void*)l, 16, 0, 0);
}

// ---------------------------------------------------------------------------
// Prep kernel (f32 inputs), block ranges (latency-heavy parts first):
//  bid [0,2048):      xa[t] = x[t,:].A[l_t] (f32, coalesced wave loads),
//                     scatter to dense xahat0/xahat1 (T x 256 bf16)
//  bid [2048,4864):   transpose B (256 x 11264 f32) -> BT (11264 x 256 bf16)
//  bid [4864,5376):   X f32 -> Xb bf16 (32 elems/thread)
//  bid [5376,8192):   W f32 -> Wb bf16 (32 elems/thread)
// ---------------------------------------------------------------------------
__global__ __launch_bounds__(256) void prep_kernel(
    const float* __restrict__ Xf, const float* __restrict__ Wf,
    const float* __restrict__ Af, const float* __restrict__ Bf,
    const int* __restrict__ widx,
    u16* __restrict__ Wb, u16* __restrict__ Xb,
    u16* __restrict__ XH0, u16* __restrict__ XH1, u16* __restrict__ BT)
{
    const int bid = blockIdx.x;
    const int tid = threadIdx.x;

    __shared__ float lx[D_DIM];          // staged x row (8 KB)
    __shared__ float red[4][8][4];
    __shared__ float xa[32];
    __shared__ u16 tile[32][33];

    if (bid < 2048) {
        // ---- xa for token t ----
        const int t = bid;
        const int l = widx[t];
        const float4* xr = (const float4*)(Xf + (size_t)t * D_DIM);
        ((float4*)lx)[tid]       = xr[tid];
        ((float4*)lx)[tid + 256] = xr[tid + 256];
        __syncthreads();

        const int wave = tid >> 6, lane = tid & 63;
        const int rowg = lane >> 3, chunk = lane & 7;
        // wave-load: 8 consecutive rows x 128 B, fully coalesced 1 KB
        const float* abase = Af + (size_t)l * (D_DIM * 32) + chunk * 4;
        float accx = 0.f, accy = 0.f, accz = 0.f, accw = 0.f;
#pragma unroll 4
        for (int i = 0; i < 64; ++i) {
            const int row = wave * 512 + i * 8 + rowg;
            const float4 av = *(const float4*)(abase + (size_t)row * 32);
            const float xf = lx[row];
            accx += xf * av.x; accy += xf * av.y;
            accz += xf * av.z; accw += xf * av.w;
        }
        // reduce across the 8 rowgroups (xor 8/16/32)
#pragma unroll
        for (int off = 8; off <= 32; off <<= 1) {
            accx += __shfl_xor(accx, off);
            accy += __shfl_xor(accy, off);
            accz += __shfl_xor(accz, off);
            accw += __shfl_xor(accw, off);
        }
        if (rowg == 0) {
            red[wave][chunk][0] = accx; red[wave][chunk][1] = accy;
            red[wave][chunk][2] = accz; red[wave][chunk][3] = accw;
        }
        __syncthreads();
        if (tid < 32) {
            const int c = tid >> 2, j = tid & 3;
            xa[c * 4 + j] = red[0][c][j] + red[1][c][j] + red[2][c][j] + red[3][c][j];
        }
        __syncthreads();
        // scatter: k = tid; xahat_h[t, l'*16+r] = (l'==l) ? xa[h*16+r] : 0
        const int k = tid, kl = k >> 4, r = k & 15;
        const bool hit = (kl == l);
        XH0[(size_t)t * KE + k] = hit ? f2bf(xa[r])      : (u16)0;
        XH1[(size_t)t * KE + k] = hit ? f2bf(xa[16 + r]) : (u16)0;
    } else if (bid < 4864) {
        // ---- 32x32 tiled transpose + convert: BT[n,k] = bf16(B[k,n]) ----
        const int b = bid - 2048;
        const int nb = b >> 3;   // 0..351
        const int kb = b & 7;    // 0..7
        const int tx = tid & 31, ty = tid >> 5;
        const int n = nb * 32 + tx;
#pragma unroll
        for (int i = 0; i < 4; ++i) {
            const int kk = kb * 32 + ty + i * 8;
            tile[ty + i * 8][tx] = f2bf(Bf[(size_t)kk * N_DIM + n]);
        }
        __syncthreads();
        const int k2 = kb * 32 + tx;
#pragma unroll
        for (int i = 0; i < 4; ++i) {
            const int n2 = nb * 32 + ty + i * 8;
            BT[(size_t)n2 * KE + k2] = tile[tx][ty + i * 8];
        }
    } else if (bid < 5376) {
        // ---- X convert: 32 f32/thread ----
        const size_t base = ((size_t)(bid - 4864) * 256 + tid) * 32;
        const float4* p = (const float4*)(Xf + base);
        float4 v[8];
#pragma unroll
        for (int i = 0; i < 8; ++i) v[i] = p[i];
#pragma unroll
        for (int i = 0; i < 4; ++i) {
            short8 o;
            o[0] = (short)f2bf(v[2*i].x);   o[1] = (short)f2bf(v[2*i].y);
            o[2] = (short)f2bf(v[2*i].z);   o[3] = (short)f2bf(v[2*i].w);
            o[4] = (short)f2bf(v[2*i+1].x); o[5] = (short)f2bf(v[2*i+1].y);
            o[6] = (short)f2bf(v[2*i+1].z); o[7] = (short)f2bf(v[2*i+1].w);
            *(short8*)(Xb + base + i * 8) = o;
        }
    } else {
        // ---- W convert: 32 f32/thread ----
        const size_t base = ((size_t)(bid - 5376) * 256 + tid) * 32;
        const float4* p = (const float4*)(Wf + base);
        float4 v[8];
#pragma unroll
        for (int i = 0; i < 8; ++i) v[i] = p[i];
#pragma unroll
        for (int i = 0; i < 4; ++i) {
            short8 o;
            o[0] = (short)f2bf(v[2*i].x);   o[1] = (short)f2bf(v[2*i].y);
            o[2] = (short)f2bf(v[2*i].z);   o[3] = (short)f2bf(v[2*i].w);
            o[4] = (short)f2bf(v[2*i+1].x); o[5] = (short)f2bf(v[2*i+1].y);
            o[6] = (short)f2bf(v[2*i+1].z); o[7] = (short)f2bf(v[2*i+1].w);
            *(short8*)(Wb + base + i * 8) = o;
        }
    }
}

// ---------------------------------------------------------------------------
// Main GEMM: out[m,n] = sum_k xb[m,k] wb[n,k]  (K=2048, bf16)
//                     + sum_k xahat_h[m,k] BT[n,k]  (K=256, h by n-half)
//
// 256x256 tile, BK=64, 512 threads = 8 waves (2M x 4N), per-wave 128x64 out.
// 36 K-tiles (32 main + 4 LoRA).
//
// Register-fragment pipeline, ONE barrier per K-tile (R3 structure, tuned):
//   static frag slots: Aa=A0(rows 0-63), Ab=A1(rows 64-127) of the wave's
//   M-half; Bz=B0(cols 0-31), Bo=B1(cols 32-63) of the wave's N-quarter.
//   Tile t sequence:
//     issue ds: B1(t):4, A1(t):8          (counted lgkm FIFO)
//     issue vm: stage B(t+1):4, A(t+1):4  (cover ~3 quads >= HBM latency)
//     lgkm(12) -> q00(Aa,Bz)    [prefetched A0/B0 complete]
//     lgkm(8)  -> q01(Aa,Bo)    [B1 complete, A1 still streaming]
//     lgkm(0)  -> q10(Ab,Bz)    [A1 complete]
//     vmcnt(0) -> s_barrier     [publish buffers t+1; drain is covered]
//     prefetch ds: B0(t+1)->Bz, A0(t+1)->Aa
//     q11(Ab,Bo)                [covers the prefetch; uses only Ab/Bo]
//   -> LDS pipe streams reads while MFMA pipe executes earlier quads; the
//   counted waits (never a blanket lgkm0 before data is needed) are what
//   R1/R4's lockstep phases lacked.
// LDS swizzle: physical 16B chunk p of row r holds global chunk p^(r&7),
// staged via pre-swizzled global source (LDS dest lane-linear as required).
// ---------------------------------------------------------------------------
__global__ __launch_bounds__(512, 2) void gemm_kernel(
    const u16* __restrict__ X, const u16* __restrict__ W,
    const u16* __restrict__ XH0, const u16* __restrict__ XH1,
    const u16* __restrict__ BT, float* __restrict__ OUT)
{
    __shared__ __align__(16) u16 lds[4][256 * 64];  // [0..1]=A dbuf, [2..3]=B dbuf

    const int tid  = threadIdx.x;
    const int lane = tid & 63;
    const int wave = tid >> 6;          // 0..7
    const int wm   = wave >> 2;         // 0..1  (M half)
    const int wn   = wave & 3;          // 0..3  (N quarter)
    const int q    = lane >> 4;         // 0..3
    const int c16  = lane & 15;

    // XCD-chunked mapping: XCD x owns bm=x, sweeps bn -> A panel L2-resident
    const int bid = blockIdx.x;
    const int bm  = bid & 7;
    const int bn  = bid >> 3;           // 0..43
    const int m0  = bm * 256, n0 = bn * 256;

    // ---- staging geometry (per gld16: 64 lanes x 16B = 8 rows x 128B) ----
    const int lrow = lane >> 3;                 // row within 8-row group
    const int gch  = (lane & 7) ^ lrow;         // pre-swizzled source chunk
    const u16* XH = (n0 < BD) ? XH0 : XH1;      // tiles never straddle halves

    const u32 offAm = (u32)((m0 + (wave << 3) + lrow) * D_DIM + gch * 8);
    const u32 offBm = (u32)((n0 + (wave << 3) + lrow) * D_DIM + gch * 8);
    const u32 offAe = (u32)((m0 + (wave << 3) + lrow) * KE + gch * 8);
    const u32 offBe = (u32)((n0 + (wave << 3) + lrow) * KE + gch * 8);

    float4v acc[8][4] = {};
    short8 Aa[8], Ab[8], Bz[4], Bo[4];

    // stage 4 gld16 units (64 rows each) of tile ktn, A-side or B-side
    auto stage4 = [&](int ktn, int isB) {
        if (ktn >= 36) return;
        u16* dst = &lds[(isB ? 2 : 0) + (ktn & 1)][0] + (wave << 3) * 64;
        if (ktn < 32) {
            const u16* src = (isB ? W + offBm : X + offAm) + ktn * 64;
#pragma unroll
            for (int i = 0; i < 4; ++i)
                gld16(src + (size_t)(i * 64) * D_DIM, dst + i * 64 * 64);
        } else {
            const u16* src = (isB ? BT + offBe : XH + offAe) + (ktn - 32) * 64;
#pragma unroll
            for (int i = 0; i < 4; ++i)
                gld16(src + (size_t)(i * 64) * KE, dst + i * 64 * 64);
        }
    };

    auto read_A = [&](short8 (&dst)[8], const u16* la, int mh) {
#pragma unroll
        for (int j = 0; j < 4; ++j)
#pragma unroll
            for (int ks = 0; ks < 2; ++ks)
                dst[j * 2 + ks] = *(const short8*)(la +
                    (wm * 128 + mh * 64 + j * 16 + c16) * 64 +
                    (((ks * 4 + q) ^ (c16 & 7)) << 3));
    };
    auto read_B = [&](short8 (&dst)[4], const u16* lb, int nh) {
#pragma unroll
        for (int f = 0; f < 2; ++f)
#pragma unroll
            for (int ks = 0; ks < 2; ++ks)
                dst[f * 2 + ks] = *(const short8*)(lb +
                    (wn * 64 + nh * 32 + f * 16 + c16) * 64 +
                    (((ks * 4 + q) ^ (c16 & 7)) << 3));
    };
    auto mma16 = [&](const short8 (&A)[8], const short8 (&B)[4], int mh, int nh) {
        __builtin_amdgcn_s_setprio(1);
#pragma unroll
        for (int j = 0; j < 4; ++j)
#pragma unroll
            for (int f = 0; f < 2; ++f)
#pragma unroll
                for (int ks = 0; ks < 2; ++ks)
                    acc[mh * 4 + j][nh * 2 + f] =
                        __builtin_amdgcn_mfma_f32_16x16x32_bf16(
                            A[j * 2 + ks], B[f * 2 + ks],
                            acc[mh * 4 + j][nh * 2 + f], 0, 0, 0);
        __builtin_amdgcn_s_setprio(0);
        __builtin_amdgcn_sched_barrier(0);
    };

#define SB0()   __builtin_amdgcn_sched_barrier(0)
#define BAR()   do { SB0(); __builtin_amdgcn_s_barrier(); SB0(); } while (0)
#define WAITL(n) do { asm volatile("s_waitcnt lgkmcnt(" #n ")" ::: "memory"); SB0(); } while (0)
#define WAITV0() do { asm volatile("s_waitcnt vmcnt(0)" ::: "memory"); SB0(); } while (0)

    // prologue: stage tile 0, publish, prefetch its A0/B0 fragments
    stage4(0, 1); stage4(0, 0);
    asm volatile("s_waitcnt vmcnt(0) lgkmcnt(0)" ::: "memory");
    BAR();
    read_B(Bz, &lds[2][0], 0);
    read_A(Aa, &lds[0][0], 0);
    SB0();

    for (int kt = 0; kt < 36; ++kt) {
        const u16* la  = &lds[kt & 1][0];
        const u16* lb  = &lds[2 + (kt & 1)][0];
        const u16* lan = &lds[(kt + 1) & 1][0];
        const u16* lbn = &lds[2 + ((kt + 1) & 1)][0];

        // issue current-tile second-half fragment reads (lgkm FIFO: B1 then A1)
        read_B(Bo, lb, 1);               // B1(kt): 4 ds_read
        read_A(Ab, la, 1);               // A1(kt): 8 ds_read
        SB0();
        // issue next-tile staging early: ~3 quads of cover before the drain
        stage4(kt + 1, 1);               // next B: 4 gld16
        stage4(kt + 1, 0);               // next A: 4 gld16
        SB0();

        WAITL(12);                       // prefetched B0,A0 landed
        mma16(Aa, Bz, 0, 0);             // q00

        WAITL(8);                        // B1 landed (A1 still streaming)
        mma16(Aa, Bo, 0, 1);             // q01

        WAITL(0);                        // A1 landed
        mma16(Ab, Bz, 1, 0);             // q10

        WAITV0();                        // next buffers staged (covered)
        BAR();                           // publish; nobody re-reads tile kt
        if (kt < 35) {
            read_B(Bz, lbn, 0);          // B0(kt+1): 4 ds_read
            read_A(Aa, lan, 0);          // A0(kt+1): 8 ds_read
            SB0();
        }
        mma16(Ab, Bo, 1, 1);             // q11 — covers the prefetch
    }

#undef SB0
#undef BAR
#undef WAITL
#undef WAITV0

    // epilogue: C/D layout col = lane&15, row = (lane>>4)*4 + reg
#pragma unroll
    for (int fm = 0; fm < 8; ++fm) {
        const size_t row = (size_t)(m0 + wm * 128 + fm * 16 + q * 4);
#pragma unroll
        for (int fn = 0; fn < 4; ++fn) {
            const int col = n0 + wn * 64 + fn * 16 + c16;
#pragma unroll
            for (int r = 0; r < 4; ++r)
                OUT[(row + r) * N_DIM + col] = acc[fm][fn][r];
        }
    }
}

extern "C" void kernel_launch(void* const* d_in, const int* in_sizes, int n_in,
                              void* d_out, int out_size, void* d_ws, size_t ws_size,
                              hipStream_t stream) {
    const float* Xf  = (const float*)d_in[0];   // (2048, 2048) f32
    const float* Wf  = (const float*)d_in[1];   // (11264, 2048) f32
    const float* Af  = (const float*)d_in[2];   // (16, 2048, 32) f32
    const float* Bf  = (const float*)d_in[3];   // (16, 16, 11264) f32
    const int* widx  = (const int*)d_in[4];     // (2048,) int32 (JAX x64 off)
    float* OUT = (float*)d_out;                 // (2048, 11264) f32

    u16* Wb  = (u16*)d_ws;                            // 11264x2048 bf16 (46.1 MB)
    u16* Xb  = Wb + (size_t)N_DIM * D_DIM;            // 2048x2048 bf16 (8.4 MB)
    u16* XH0 = Xb + (size_t)T_DIM * D_DIM;            // 2048x256 bf16 (1 MB)
    u16* XH1 = XH0 + (size_t)T_DIM * KE;              // 2048x256 bf16 (1 MB)
    u16* BT  = XH1 + (size_t)T_DIM * KE;              // 11264x256 bf16 (5.5 MB)

    prep_kernel<<<dim3(8192), dim3(256), 0, stream>>>(Xf, Wf, Af, Bf, widx,
                                                      Wb, Xb, XH0, XH1, BT);
    gemm_kernel<<<dim3(352), dim3(512), 0, stream>>>(
        Xb, Wb, XH0, XH1, BT, OUT);
}